// Round 2
// baseline (824.698 us; speedup 1.0000x reference)
//
#include <hip/hip_runtime.h>
#include <cstdint>

typedef _Float16 f16;
typedef __attribute__((ext_vector_type(8))) _Float16 half8;
typedef __attribute__((ext_vector_type(4))) float floatx4;

#define NB      40000
#define M_TOTAL 80000
#define DIN     1024
#define LDIM    512
#define DDIM    384

// ---------------- kernel 0: pack weights into MFMA B-fragment order --------
// packedF[((kb*512 + n)*4 + lq)*8 + j] = f16(Wf[(kb*32 + lq*8 + j)*512 + n]), kb<32
// packedAB: cols c<768 interleave a/g per 16: d=(c>>5)*16+(c&15), type=(c>>4)&1
__global__ void k_prep(const float* __restrict__ Wf, const float* __restrict__ Wa,
                       const float* __restrict__ Wb,
                       f16* __restrict__ packedF, f16* __restrict__ packedAB)
{
    const int gid = blockIdx.x * 256 + threadIdx.x;
    if (gid < 65536) {
        const int lq = gid & 3, n = (gid >> 2) & 511, kb = gid >> 11;
        const int kbase = kb * 32 + lq * 8;
        half8 v;
        #pragma unroll
        for (int j = 0; j < 8; ++j) v[j] = (f16)Wf[(kbase + j) * 512 + n];
        *(half8*)&packedF[(long)gid * 8] = v;
    } else if (gid < 65536 + 49152) {
        const int g = gid - 65536;
        const int kb = g / 3072;
        const int rem = g - kb * 3072;
        const int c = rem >> 2, lq = rem & 3;
        const int d = ((c >> 5) << 4) + (c & 15);
        const int type = (c >> 4) & 1;
        const float* src = type ? Wb : Wa;
        const int kbase = kb * 32 + lq * 8;
        half8 v;
        #pragma unroll
        for (int j = 0; j < 8; ++j) v[j] = (f16)src[(kbase + j) * 384 + d];
        *(half8*)&packedAB[(long)g * 8] = v;
    }
}

// ---------------- kernel 1: h = relu(x @ Wf + bf), f16 out ------------------
// 512 thr = 8 waves; block = 64 rows x 512 cols (full N -> x read once).
// Wave w: cols [w*64, w*64+64) as 4 MFMA col-tiles; acc[4][4] (64 VGPR).
// A in LDS (f16, dbuf, 1 barrier/iter); B fragments direct from packedF (L2).
__global__ __launch_bounds__(512, 4) void k_gemm1(
    const float* __restrict__ x, const f16* __restrict__ packedF,
    const float* __restrict__ bf, f16* __restrict__ h)
{
    __shared__ __align__(16) f16 As[2][64][72];   // 72-stride: 2-way banks only (free)
    const int tid = threadIdx.x;
    const int w = tid >> 6, lane = tid & 63, lr = lane & 15, lq = lane >> 4;
    const long row0 = (long)blockIdx.x * 64;
    const int sr = tid >> 3, sk = (tid & 7) * 8;     // stage: 8 floats/thread
    const float* xp = x + (row0 + sr) * DIN + sk;

    floatx4 acc[4][4] = {};

    float4 xa = *(const float4*)xp;
    float4 xb = *(const float4*)(xp + 4);
    {
        half8 hv;
        hv[0]=(f16)xa.x; hv[1]=(f16)xa.y; hv[2]=(f16)xa.z; hv[3]=(f16)xa.w;
        hv[4]=(f16)xb.x; hv[5]=(f16)xb.y; hv[6]=(f16)xb.z; hv[7]=(f16)xb.w;
        *(half8*)&As[0][sr][sk] = hv;
    }
    for (int kt = 0; kt < 16; ++kt) {          // BK=64, 16 iters
        __syncthreads();
        const int cur = kt & 1;
        if (kt < 15) {                         // prefetch next A chunk (global)
            const float* q = xp + (kt + 1) * 64;
            xa = *(const float4*)q;
            xb = *(const float4*)(q + 4);
        }
        #pragma unroll
        for (int kq = 0; kq < 2; ++kq) {
            const int kb = kt * 2 + kq;
            half8 bfr[4];
            #pragma unroll
            for (int tj = 0; tj < 4; ++tj)
                bfr[tj] = *(const half8*)&packedF[(long)((kb * 512 + w * 64 + tj * 16 + lr) << 5) + lq * 8];
            half8 af[4];
            #pragma unroll
            for (int ti = 0; ti < 4; ++ti)
                af[ti] = *(const half8*)&As[cur][ti * 16 + lr][kq * 32 + lq * 8];
            #pragma unroll
            for (int tj = 0; tj < 4; ++tj)
                #pragma unroll
                for (int ti = 0; ti < 4; ++ti)
                    acc[ti][tj] = __builtin_amdgcn_mfma_f32_16x16x32_f16(af[ti], bfr[tj], acc[ti][tj], 0, 0, 0);
        }
        if (kt < 15) {                         // cvt + write next buffer
            half8 hv;
            hv[0]=(f16)xa.x; hv[1]=(f16)xa.y; hv[2]=(f16)xa.z; hv[3]=(f16)xa.w;
            hv[4]=(f16)xb.x; hv[5]=(f16)xb.y; hv[6]=(f16)xb.z; hv[7]=(f16)xb.w;
            *(half8*)&As[cur ^ 1][sr][sk] = hv;
        }
    }
    // epilogue: +bias, relu, f16 store. C/D: col=lr, row=lq*4+r
    #pragma unroll
    for (int tj = 0; tj < 4; ++tj) {
        const int col = w * 64 + tj * 16 + lr;
        const float bias = bf[col];
        #pragma unroll
        for (int ti = 0; ti < 4; ++ti) {
            const long rbase = row0 + ti * 16 + lq * 4;
            #pragma unroll
            for (int r = 0; r < 4; ++r) {
                float v = fmaxf(acc[ti][tj][r] + bias, 0.0f);
                h[(rbase + r) * LDIM + col] = (f16)v;
            }
        }
    }
}

// ---------------- kernel 2: gated attention scores --------------------------
__device__ inline float fast_sigmoid(float xx) { return 1.0f / (1.0f + __expf(-xx)); }
__device__ inline float fast_tanh(float xx) {
    float e = __expf(-2.0f * fabsf(xx));
    float r = (1.0f - e) / (1.0f + e);
    return xx >= 0.0f ? r : -r;
}

// 512 thr = 8 waves; block = 64 rows x 768 packed cols; wave w: cols [w*96,+96)
// = 3 (a,g) tile-pairs. acc[4][6]. h tile in LDS (dbuf), B from packedAB (L2).
// bc omitted: constant shift cancels in softmax over n.
__global__ __launch_bounds__(512, 2) void k_gemm2(
    const f16* __restrict__ h, const f16* __restrict__ packedAB,
    const float* __restrict__ ba, const float* __restrict__ bb,
    const float* __restrict__ Wc, float* __restrict__ s)
{
    __shared__ __align__(16) f16 Hs[2][64][136];  // 136-stride: 2-way banks (free)
    const int tid = threadIdx.x;
    const int w = tid >> 6, lane = tid & 63, lr = lane & 15, lq = lane >> 4;
    const long row0 = (long)blockIdx.x * 64;
    const int sr = tid >> 3, sk = (tid & 7) * 16;  // stage: 16 f16/thread
    const f16* hp = h + (row0 + sr) * LDIM + sk;

    floatx4 acc[4][6] = {};

    half8 s0 = *(const half8*)hp;
    half8 s1 = *(const half8*)(hp + 8);
    *(half8*)&Hs[0][sr][sk]     = s0;
    *(half8*)&Hs[0][sr][sk + 8] = s1;

    for (int kt = 0; kt < 4; ++kt) {           // BK=128, 4 iters
        __syncthreads();
        const int cur = kt & 1;
        if (kt < 3) {
            const f16* q = hp + (kt + 1) * 128;
            s0 = *(const half8*)q;
            s1 = *(const half8*)(q + 8);
        }
        #pragma unroll
        for (int kq = 0; kq < 4; ++kq) {
            const int kb = kt * 4 + kq;
            half8 af[4];
            #pragma unroll
            for (int ti = 0; ti < 4; ++ti)
                af[ti] = *(const half8*)&Hs[cur][ti * 16 + lr][kq * 32 + lq * 8];
            #pragma unroll
            for (int tj = 0; tj < 6; ++tj) {
                half8 bfr = *(const half8*)&packedAB[(long)((kb * 768 + w * 96 + tj * 16 + lr) << 5) + lq * 8];
                #pragma unroll
                for (int ti = 0; ti < 4; ++ti)
                    acc[ti][tj] = __builtin_amdgcn_mfma_f32_16x16x32_f16(af[ti], bfr, acc[ti][tj], 0, 0, 0);
            }
        }
        if (kt < 3) {
            *(half8*)&Hs[cur ^ 1][sr][sk]     = s0;
            *(half8*)&Hs[cur ^ 1][sr][sk + 8] = s1;
        }
    }
    // epilogue: tile pair (2u, 2u+1) share d = w*48 + u*16 + lr
    float sp[4][4] = {};
    #pragma unroll
    for (int u = 0; u < 3; ++u) {
        const int d = w * 48 + u * 16 + lr;
        const float biasA = ba[d], biasB = bb[d], wcv = Wc[d];
        #pragma unroll
        for (int ti = 0; ti < 4; ++ti)
            #pragma unroll
            for (int r = 0; r < 4; ++r) {
                const float av = fast_tanh(acc[ti][2 * u][r] + biasA);
                const float gv = fast_sigmoid(acc[ti][2 * u + 1][r] + biasB);
                sp[ti][r] += av * gv * wcv;
            }
    }
    #pragma unroll
    for (int m = 1; m < 16; m <<= 1)
        #pragma unroll
        for (int ti = 0; ti < 4; ++ti)
            #pragma unroll
            for (int r = 0; r < 4; ++r)
                sp[ti][r] += __shfl_xor(sp[ti][r], m, 64);
    if (lr == 0) {
        #pragma unroll
        for (int ti = 0; ti < 4; ++ti)
            #pragma unroll
            for (int r = 0; r < 4; ++r)
                atomicAdd(&s[row0 + ti * 16 + lq * 4 + r], sp[ti][r]);
    }
}

// ---------------- kernel 3: per-batch softmax stats ----------------
__global__ void k_stats(const float* __restrict__ s, float* __restrict__ stats)
{
    const int b = blockIdx.x;
    const int tid = threadIdx.x; // 256
    const float* sb = s + b * NB;
    __shared__ float red[4];
    __shared__ float red2[4];
    __shared__ float smax_sh;
    float m = -3.4e38f;
    for (int i = tid; i < NB; i += 256) m = fmaxf(m, sb[i]);
    #pragma unroll
    for (int o = 32; o > 0; o >>= 1) m = fmaxf(m, __shfl_xor(m, o, 64));
    if ((tid & 63) == 0) red[tid >> 6] = m;
    __syncthreads();
    if (tid == 0) smax_sh = fmaxf(fmaxf(red[0], red[1]), fmaxf(red[2], red[3]));
    __syncthreads();
    const float smax = smax_sh;
    float sum = 0.0f;
    for (int i = tid; i < NB; i += 256) sum += __expf(sb[i] - smax);
    #pragma unroll
    for (int o = 32; o > 0; o >>= 1) sum += __shfl_xor(sum, o, 64);
    if ((tid & 63) == 0) red2[tid >> 6] = sum;
    __syncthreads();
    if (tid == 0) {
        stats[b * 2]     = smax;
        stats[b * 2 + 1] = red2[0] + red2[1] + red2[2] + red2[3];
    }
}

// ---------------- kernel 4: pooled += exp(s-max) * h ----------------
// 500 blocks = 2 batches x 250 chunks of 160 rows; half8 loads, LDS reduce.
__global__ __launch_bounds__(256) void k_pool(
    const f16* __restrict__ h, const float* __restrict__ s,
    const float* __restrict__ stats, float* __restrict__ pooled)
{
    __shared__ float red[4][512];
    const int bx = blockIdx.x;
    const int b = bx / 250, ch = bx - b * 250;
    const float smax = stats[b * 2];
    const int tid = threadIdx.x;
    const int rg = tid >> 6, cl = (tid & 63) * 8;
    const long nbase = (long)b * NB + ch * 160;
    float a[8] = {};
    for (int r = rg; r < 160; r += 4) {
        const long n = nbase + r;
        const float wgt = __expf(s[n] - smax);
        half8 hv = *(const half8*)&h[n * LDIM + cl];
        #pragma unroll
        for (int j = 0; j < 8; ++j) a[j] += wgt * (float)hv[j];
    }
    #pragma unroll
    for (int j = 0; j < 8; ++j) red[rg][cl + j] = a[j];
    __syncthreads();
    if (rg == 0) {
        #pragma unroll
        for (int j = 0; j < 8; ++j) {
            const int c = cl + j;
            atomicAdd(&pooled[b * LDIM + c], red[0][c] + red[1][c] + red[2][c] + red[3][c]);
        }
    }
}

// ---------------- kernel 5: logits ----------------
__global__ void k_logits(const float* __restrict__ pooled, const float* __restrict__ stats,
                         const float* __restrict__ Wcls, const float* __restrict__ bcls,
                         float* __restrict__ out)
{
    const int tid = threadIdx.x;  // 256 = 4 waves; wave -> (b,c)
    const int wave = tid >> 6, lane = tid & 63;
    const int b = wave >> 1, c = wave & 1;
    float sum = 0.0f;
    for (int l = lane; l < LDIM; l += 64)
        sum += pooled[b * LDIM + l] * Wcls[l * 2 + c];
    #pragma unroll
    for (int o = 32; o > 0; o >>= 1) sum += __shfl_xor(sum, o, 64);
    if (lane == 0) out[b * 2 + c] = sum / stats[b * 2 + 1] + bcls[c];
}

// ---------------- launch ----------------
extern "C" void kernel_launch(void* const* d_in, const int* in_sizes, int n_in,
                              void* d_out, int out_size, void* d_ws, size_t ws_size,
                              hipStream_t stream)
{
    const float* x    = (const float*)d_in[0];
    const float* Wf   = (const float*)d_in[1];
    const float* bf   = (const float*)d_in[2];
    const float* Wa   = (const float*)d_in[3];
    const float* ba   = (const float*)d_in[4];
    const float* Wb   = (const float*)d_in[5];
    const float* bb   = (const float*)d_in[6];
    const float* Wc   = (const float*)d_in[7];
    // d_in[8] = bc: constant shift over n, cancels in softmax -> unused
    const float* Wcls = (const float*)d_in[9];
    const float* bcls = (const float*)d_in[10];
    float* out = (float*)d_out;

    // workspace layout (16B aligned), total 84,079,232 B
    char* w = (char*)d_ws;
    f16*   packedF  = (f16*)(w);                  // 1,048,576
    f16*   packedAB = (f16*)(w + 1048576);        //   786,432
    f16*   hbuf     = (f16*)(w + 1835008);        // 81,920,000
    float* sbuf     = (float*)(w + 83755008);     //   320,000
    float* stats    = (float*)(w + 84075008);     //       128
    float* pooled   = (float*)(w + 84075136);     //     4,096

    hipMemsetAsync(sbuf, 0, 320000, stream);
    hipMemsetAsync(pooled, 0, 4096, stream);

    k_prep  <<<448, 256, 0, stream>>>(Wf, Wa, Wb, packedF, packedAB);
    k_gemm1 <<<M_TOTAL / 64, 512, 0, stream>>>(x, packedF, bf, hbuf);
    k_gemm2 <<<M_TOTAL / 64, 512, 0, stream>>>(hbuf, packedAB, ba, bb, Wc, sbuf);
    k_stats <<<2, 256, 0, stream>>>(sbuf, stats);
    k_pool  <<<500, 256, 0, stream>>>(hbuf, sbuf, stats, pooled);
    k_logits<<<1, 256, 0, stream>>>(pooled, stats, Wcls, bcls, out);
}

// Round 3
// 717.156 us; speedup vs baseline: 1.1500x; 1.1500x over previous
//
#include <hip/hip_runtime.h>
#include <cstdint>

typedef _Float16 f16;
typedef __attribute__((ext_vector_type(8))) _Float16 half8;
typedef __attribute__((ext_vector_type(4))) float floatx4;

#define NB      40000
#define M_TOTAL 80000
#define DIN     1024
#define LDIM    512
#define NBLK    1250   // 64-row blocks
#define BPB     625    // blocks per batch

// ---------------- kernel 0: pack weights into MFMA B-fragment order --------
// packedF[((kb*512 + n)*4 + lq)*8 + j] = f16(Wf[(kb*32 + lq*8 + j)*512 + n]), kb<32
// packedAB: cols c<768 interleave a/g per 16: d=(c>>5)*16+(c&15), type=(c>>4)&1
__global__ void k_prep(const float* __restrict__ Wf, const float* __restrict__ Wa,
                       const float* __restrict__ Wb,
                       f16* __restrict__ packedF, f16* __restrict__ packedAB)
{
    const int gid = blockIdx.x * 256 + threadIdx.x;
    if (gid < 65536) {
        const int lq = gid & 3, n = (gid >> 2) & 511, kb = gid >> 11;
        const int kbase = kb * 32 + lq * 8;
        half8 v;
        #pragma unroll
        for (int j = 0; j < 8; ++j) v[j] = (f16)Wf[(kbase + j) * 512 + n];
        *(half8*)&packedF[(long)gid * 8] = v;
    } else if (gid < 65536 + 49152) {
        const int g = gid - 65536;
        const int kb = g / 3072;
        const int rem = g - kb * 3072;
        const int c = rem >> 2, lq = rem & 3;
        const int d = ((c >> 5) << 4) + (c & 15);
        const int type = (c >> 4) & 1;
        const float* src = type ? Wb : Wa;
        const int kbase = kb * 32 + lq * 8;
        half8 v;
        #pragma unroll
        for (int j = 0; j < 8; ++j) v[j] = (f16)src[(kbase + j) * 384 + d];
        *(half8*)&packedAB[(long)g * 8] = v;
    }
}

__device__ inline float fast_sigmoid(float xx) { return 1.0f / (1.0f + __expf(-xx)); }
__device__ inline float fast_tanh(float xx) {
    float e = __expf(-2.0f * fabsf(xx));
    float r = (1.0f - e) / (1.0f + e);
    return xx >= 0.0f ? r : -r;
}

// ---------------- kernel 1: fully fused per-64-row pipeline -----------------
// x-tile -> h (LDS) -> a/g -> s -> e^s -> partial pooled sums. h never hits HBM.
// No softmax max-subtraction: e^s ratio is shift-invariant; |s|<=||Wc||_1 ~ 22.
__global__ __launch_bounds__(512, 4) void k_fused(
    const float* __restrict__ x, const f16* __restrict__ packedF,
    const f16* __restrict__ packedAB,
    const float* __restrict__ bf, const float* __restrict__ ba,
    const float* __restrict__ bb, const float* __restrict__ Wc,
    float* __restrict__ partial_pool, float* __restrict__ partial_denom)
{
    __shared__ __align__(16) f16 Hs[64][520];   // stride 520: quad-uniform b128 frags
    __shared__ __align__(16) f16 As[64][72];
    __shared__ float wbuf[64];
    const int tid = threadIdx.x;
    const int w = tid >> 6, lane = tid & 63, lr = lane & 15, lq = lane >> 4;
    const long row0 = (long)blockIdx.x * 64;
    const int sr = tid >> 3, st = (tid & 7) * 8;     // stage: 8 floats/thread
    const float* xp = x + (row0 + sr) * DIN + st;
    if (tid < 64) wbuf[tid] = 0.0f;

    // ---------------- phase 1: h-tile = relu(x @ Wf + bf) ----------------
    floatx4 acc[4][4] = {};
    float4 xa = *(const float4*)xp;
    float4 xb = *(const float4*)(xp + 4);
    for (int kt = 0; kt < 16; ++kt) {                // BK=64
        __syncthreads();                             // As free to overwrite
        {
            half8 hv;
            hv[0]=(f16)xa.x; hv[1]=(f16)xa.y; hv[2]=(f16)xa.z; hv[3]=(f16)xa.w;
            hv[4]=(f16)xb.x; hv[5]=(f16)xb.y; hv[6]=(f16)xb.z; hv[7]=(f16)xb.w;
            *(half8*)&As[sr][st] = hv;
        }
        __syncthreads();                             // stage visible
        if (kt < 15) {                               // prefetch lands during MFMAs
            const float* q = xp + (kt + 1) * 64;
            xa = *(const float4*)q;
            xb = *(const float4*)(q + 4);
        }
        #pragma unroll
        for (int kq = 0; kq < 2; ++kq) {
            const int kb = kt * 2 + kq;
            half8 bfr[4];
            #pragma unroll
            for (int tj = 0; tj < 4; ++tj)
                bfr[tj] = *(const half8*)&packedF[(long)((kb * 512 + w * 64 + tj * 16 + lr) << 5) + lq * 8];
            half8 af[4];
            #pragma unroll
            for (int ti = 0; ti < 4; ++ti)
                af[ti] = *(const half8*)&As[ti * 16 + lr][kq * 32 + lq * 8];
            #pragma unroll
            for (int tj = 0; tj < 4; ++tj)
                #pragma unroll
                for (int ti = 0; ti < 4; ++ti)
                    acc[ti][tj] = __builtin_amdgcn_mfma_f32_16x16x32_f16(af[ti], bfr[tj], acc[ti][tj], 0, 0, 0);
        }
    }
    // epilogue -> Hs (LDS only). C/D: col=lr, row=lq*4+r
    #pragma unroll
    for (int tj = 0; tj < 4; ++tj) {
        const int col = w * 64 + tj * 16 + lr;
        const float bias = bf[col];
        #pragma unroll
        for (int ti = 0; ti < 4; ++ti)
            #pragma unroll
            for (int r = 0; r < 4; ++r)
                Hs[ti * 16 + lq * 4 + r][col] = (f16)fmaxf(acc[ti][tj][r] + bias, 0.0f);
    }
    __syncthreads();                                 // h-tile complete

    // ---------------- phase 2: a/g GEMM from LDS (no barriers) ------------
    floatx4 acc2[4][6] = {};
    for (int kb = 0; kb < 16; ++kb) {                // K=512
        half8 af[4];
        #pragma unroll
        for (int ti = 0; ti < 4; ++ti)
            af[ti] = *(const half8*)&Hs[ti * 16 + lr][kb * 32 + lq * 8];
        #pragma unroll
        for (int tj = 0; tj < 6; ++tj) {
            half8 bfr = *(const half8*)&packedAB[(long)((kb * 768 + w * 96 + tj * 16 + lr) << 5) + lq * 8];
            #pragma unroll
            for (int ti = 0; ti < 4; ++ti)
                acc2[ti][tj] = __builtin_amdgcn_mfma_f32_16x16x32_f16(af[ti], bfr, acc2[ti][tj], 0, 0, 0);
        }
    }
    // epilogue: s_row += sum_d tanh(a+ba)*sigmoid(g+bb)*Wc[d]   (bc cancels)
    float sp[4][4] = {};
    #pragma unroll
    for (int u = 0; u < 3; ++u) {
        const int d = w * 48 + u * 16 + lr;
        const float biasA = ba[d], biasB = bb[d], wcv = Wc[d];
        #pragma unroll
        for (int ti = 0; ti < 4; ++ti)
            #pragma unroll
            for (int r = 0; r < 4; ++r) {
                const float av = fast_tanh(acc2[ti][2 * u][r] + biasA);
                const float gv = fast_sigmoid(acc2[ti][2 * u + 1][r] + biasB);
                sp[ti][r] += av * gv * wcv;
            }
    }
    #pragma unroll
    for (int m = 1; m < 16; m <<= 1)
        #pragma unroll
        for (int ti = 0; ti < 4; ++ti)
            #pragma unroll
            for (int r = 0; r < 4; ++r)
                sp[ti][r] += __shfl_xor(sp[ti][r], m, 64);
    if (lr == 0) {
        #pragma unroll
        for (int ti = 0; ti < 4; ++ti)
            #pragma unroll
            for (int r = 0; r < 4; ++r)
                atomicAdd(&wbuf[ti * 16 + lq * 4 + r], sp[ti][r]);
    }
    __syncthreads();
    if (tid < 64) wbuf[tid] = __expf(wbuf[tid]);     // attention weights (unnormalized)
    __syncthreads();

    // ---------------- phase 3: partial pooled sums ------------------------
    {
        const int c = tid;                            // 512 threads <-> 512 cols
        float pacc = 0.0f;
        #pragma unroll 8
        for (int n = 0; n < 64; ++n)
            pacc += wbuf[n] * (float)Hs[n][c];
        partial_pool[(long)blockIdx.x * 512 + c] = pacc;
    }
    if (w == 0) {                                     // wave 0: denom partial
        float dsum = wbuf[lane];
        #pragma unroll
        for (int o = 32; o > 0; o >>= 1) dsum += __shfl_xor(dsum, o, 64);
        if (lane == 0) partial_denom[blockIdx.x] = dsum;
    }
}

// ---------------- kernel 2: reduce partials + logits ------------------------
__global__ __launch_bounds__(512) void k_reduce(
    const float* __restrict__ pp, const float* __restrict__ pd,
    const float* __restrict__ Wcls, const float* __restrict__ bcls,
    float* __restrict__ out)
{
    __shared__ float pooled[512];
    __shared__ float dsh[8];
    const int b = blockIdx.x, tid = threadIdx.x;
    float acc = 0.0f;
    const float* base = pp + (long)b * BPB * 512 + tid;
    for (int i = 0; i < BPB; ++i) acc += base[(long)i * 512];
    pooled[tid] = acc;
    float d = 0.0f;
    for (int i = tid; i < BPB; i += 512) d += pd[b * BPB + i];
    #pragma unroll
    for (int o = 32; o > 0; o >>= 1) d += __shfl_xor(d, o, 64);
    if ((tid & 63) == 0) dsh[tid >> 6] = d;
    __syncthreads();
    const float denom = dsh[0] + dsh[1] + dsh[2] + dsh[3] + dsh[4] + dsh[5] + dsh[6] + dsh[7];
    if (tid < 128) {                                  // 2 waves: cls = wave
        const int cls = tid >> 6, ln = tid & 63;
        float sum = 0.0f;
        #pragma unroll
        for (int t = 0; t < 8; ++t)
            sum += pooled[t * 64 + ln] * Wcls[(t * 64 + ln) * 2 + cls];
        #pragma unroll
        for (int o = 32; o > 0; o >>= 1) sum += __shfl_xor(sum, o, 64);
        if (ln == 0) out[b * 2 + cls] = sum / denom + bcls[cls];
    }
}

// ---------------- launch ----------------
extern "C" void kernel_launch(void* const* d_in, const int* in_sizes, int n_in,
                              void* d_out, int out_size, void* d_ws, size_t ws_size,
                              hipStream_t stream)
{
    const float* x    = (const float*)d_in[0];
    const float* Wf   = (const float*)d_in[1];
    const float* bf   = (const float*)d_in[2];
    const float* Wa   = (const float*)d_in[3];
    const float* ba   = (const float*)d_in[4];
    const float* Wb   = (const float*)d_in[5];
    const float* bb   = (const float*)d_in[6];
    const float* Wc   = (const float*)d_in[7];
    // d_in[8] = bc: constant shift over n, cancels in the softmax ratio -> unused
    const float* Wcls = (const float*)d_in[9];
    const float* bcls = (const float*)d_in[10];
    float* out = (float*)d_out;

    // workspace layout (16B aligned), total ~4.4 MB
    char* w = (char*)d_ws;
    f16*   packedF  = (f16*)(w);                   // 1,048,576
    f16*   packedAB = (f16*)(w + 1048576);         //   786,432
    float* ppool    = (float*)(w + 1835008);       // 2,560,000 (1250 x 512 fp32)
    float* pdenom   = (float*)(w + 4395008);       //     5,000

    k_prep  <<<448, 256, 0, stream>>>(Wf, Wa, Wb, packedF, packedAB);
    k_fused <<<NBLK, 512, 0, stream>>>(x, packedF, packedAB, bf, ba, bb, Wc, ppool, pdenom);
    k_reduce<<<2, 512, 0, stream>>>(ppool, pdenom, Wcls, bcls, out);
}